// Round 10
// baseline (117.127 us; speedup 1.0000x reference)
//
#include <hip/hip_runtime.h>
#include <hip/hip_bf16.h>

#define NB 8
#define NT 2048
#define NE 1024
#define NH 64

typedef __bf16 bf16_t;
typedef __bf16 bf16x8 __attribute__((ext_vector_type(8)));
typedef float f32x4 __attribute__((ext_vector_type(4)));

#define MFMA16(a, b, c) __builtin_amdgcn_mfma_f32_16x16x32_bf16(a, b, c, 0, 0, 0)

static __device__ __forceinline__ f32x4 fzero4() {
    f32x4 z = {0.f, 0.f, 0.f, 0.f};
    return z;
}

// async global -> LDS, 16 B per lane. LDS dest is wave-uniform base + lane*16
// (HW rule, m104/m108); global src is per-lane (pre-swizzle goes on the src).
static __device__ __forceinline__ void gload_lds16(const void* gsrc, void* ldst) {
    __builtin_amdgcn_global_load_lds(
        (const __attribute__((address_space(1))) char*)gsrc,
        (__attribute__((address_space(3))) char*)ldst, 16, 0, 0);
}

// ---------------------------------------------------------------------------
// Kernel 0: convert W (f32) -> bf16 workspace. Wb layout: [0]=Wq, [1]=Wk, [2]=Wv
// ---------------------------------------------------------------------------
__global__ __launch_bounds__(256) void convw_kernel(
    const float* __restrict__ Wq, const float* __restrict__ Wk,
    const float* __restrict__ Wv, bf16_t* __restrict__ Wb)
{
    int src = blockIdx.y;
    const float* W = (src == 0) ? Wq : ((src == 1) ? Wk : Wv);
    int idx = (blockIdx.x * 256 + threadIdx.x) * 8;  // 32 blocks * 256 thr * 8 = 65536
    f32x4 a = *(const f32x4*)(W + idx);
    f32x4 b = *(const f32x4*)(W + idx + 4);
    bf16x8 o;
#pragma unroll
    for (int j = 0; j < 4; ++j) { o[j] = (bf16_t)a[j]; o[4 + j] = (bf16_t)b[j]; }
    *(bf16x8*)(Wb + (size_t)src * (NH * NE) + idx) = o;
}

// ---------------------------------------------------------------------------
// Kernel 1: projections, ONE-SHOT burst staging (R10).
// Every prior structure (R2..R9) delivered the x stream at ~2-2.3 TB/s:
// 128-256B chunks at 4KB row stride (DRAM-page-hostile) with only 2-8 KB
// outstanding per wave. R10: block = one 16-row t-tile; the 4 waves stage
// the WHOLE [16][1024] f32 x-tile (64 KB) in one burst -- each row read as
// 4KB of consecutive addresses (4 x 1KB gload_lds), 16 stage + 32 W loads
// per wave ALL in flight (~128 KB/CU outstanding). W K-slices hoisted to
// registers once; the 8-step MFMA loop then has ZERO VMEM. K-split-4 merge
// through LDS (R9's barrier-fixed pattern, aliased union).
// Chunk swizzle: LDS phys chunk p of row r holds logical chunk p^(r&15)
// (low-4-bit XOR stays inside each instr's 1KB span -> global coalescing
// intact; read side spreads 16 rows over 8 bank-quads = conflict-free b128).
//   y=0: qh[t][h] = q . Wq   (A = x rows, B = W)
//   y=1: kh[t][h] = k . Wk
//   y=2: vhT[b][h][t] = v . Wv (A = W, B = x -> accumulator is [h][t])
// MFMA 16x16x32 conventions (m89/m91-verified):
//   A-frag: lane holds A[row=lane&15][k=(lane>>4)*8 + j]
//   B-frag: lane holds B[k=(lane>>4)*8 + j][col=lane&15]
//   D:      col = lane&15, row = (lane>>4)*4 + reg
// ---------------------------------------------------------------------------
__global__ __launch_bounds__(256) void proj_kernel(
    const float* __restrict__ q_in, const float* __restrict__ k_in,
    const float* __restrict__ v_in, const bf16_t* __restrict__ Wb,
    bf16_t* __restrict__ qh, bf16_t* __restrict__ kh, bf16_t* __restrict__ vhT)
{
    const int which = blockIdx.y;
    const int w    = threadIdx.x >> 6;   // K-split index 0..3 (K slice w*256..+256)
    const int lane = threadIdx.x & 63;
    const int l15  = lane & 15;
    const int lhi  = lane >> 4;
    const int t0   = blockIdx.x * 16;

    const float*  x = (which == 0) ? q_in : ((which == 1) ? k_in : v_in);
    const bf16_t* W = Wb + (size_t)which * (NH * NE);

    // stage: [row][256 chunks of 16B], chunk XOR-swizzled by row (low 4 bits)
    // mq/mv: merge scratch (aliased; only touched after the pre-merge barrier)
    __shared__ __align__(16) union {
        char  stage[16][4096];
        float mq[4][16][65];
        float mv[4][64][17];
    } sm;

    // ---- one-shot stage burst: wave w stages rows 4w..4w+3 --------------
    // instr (rr,q): 64 lanes x 16B = 1 KB = quarter q of row, contiguous.
#pragma unroll
    for (int j = 0; j < 16; ++j) {
        const int row = w * 4 + (j >> 2);
        const int q   = j & 3;
        const float* src = x + (size_t)(t0 + row) * NE + q * 256
                             + (lane ^ (row & 15)) * 4;
        gload_lds16(src, &sm.stage[row][q * 1024]);
    }

    // ---- hoist this wave's W K-slice (64h x 256K bf16) into registers ----
    const bf16_t* wbase = W + (size_t)l15 * NE + w * 256 + lhi * 8;
    bf16x8 wf[8][4];
#pragma unroll
    for (int s = 0; s < 8; ++s)
#pragma unroll
        for (int cg = 0; cg < 4; ++cg)
            wf[s][cg] = *(const bf16x8*)(wbase + (size_t)cg * 16 * NE + s * 32);

    // barrier (compiler emits vmcnt(0) drain): all 16 rows staged, W landed
    __syncthreads();

    f32x4 acc[4] = {fzero4(), fzero4(), fzero4(), fzero4()};

    // ---- K-loop: 8 steps of K=32, pure LDS + VALU + MFMA (zero VMEM) ----
#pragma unroll
    for (int s = 0; s < 8; ++s) {
        const int c0 = w * 64 + s * 8 + lhi * 2;   // logical 16B chunk
        f32x4 a0 = *(const f32x4*)(&sm.stage[l15][((c0    ) ^ (l15 & 15)) * 16]);
        f32x4 a1 = *(const f32x4*)(&sm.stage[l15][((c0 + 1) ^ (l15 & 15)) * 16]);
        bf16x8 xf;
#pragma unroll
        for (int j = 0; j < 4; ++j) { xf[j] = (bf16_t)a0[j]; xf[4 + j] = (bf16_t)a1[j]; }

        if (which < 2) {
            acc[0] = MFMA16(xf, wf[s][0], acc[0]);
            acc[1] = MFMA16(xf, wf[s][1], acc[1]);
            acc[2] = MFMA16(xf, wf[s][2], acc[2]);
            acc[3] = MFMA16(xf, wf[s][3], acc[3]);
        } else {
            acc[0] = MFMA16(wf[s][0], xf, acc[0]);
            acc[1] = MFMA16(wf[s][1], xf, acc[1]);
            acc[2] = MFMA16(wf[s][2], xf, acc[2]);
            acc[3] = MFMA16(wf[s][3], xf, acc[3]);
        }
    }

    // ---- all waves must finish reading stage LDS before any wave
    // repurposes the (aliased) region as merge scratch (R9 fix) -----------
    __syncthreads();

    // ---- merge the 4 K-splits through LDS --------------------------------
    if (which < 2) {
        // partial is [16 rows][64 cols]
#pragma unroll
        for (int cg = 0; cg < 4; ++cg)
#pragma unroll
            for (int r = 0; r < 4; ++r)
                sm.mq[w][lhi * 4 + r][cg * 16 + l15] = acc[cg][r];
        __syncthreads();
        bf16_t* outp = (which == 0) ? qh : kh;
        const int col = w * 16 + l15;   // w repurposed as column group
#pragma unroll
        for (int r = 0; r < 4; ++r) {
            int row = lhi * 4 + r;
            float v = sm.mq[0][row][col] + sm.mq[1][row][col] +
                      sm.mq[2][row][col] + sm.mq[3][row][col];
            outp[(size_t)(t0 + row) * NH + col] = (bf16_t)v;
        }
    } else {
        // partial is [64 h][16 t]
#pragma unroll
        for (int hg = 0; hg < 4; ++hg)
#pragma unroll
            for (int r = 0; r < 4; ++r)
                sm.mv[w][hg * 16 + lhi * 4 + r][l15] = acc[hg][r];
        __syncthreads();
        const int tg = t0 + l15;
        const int b  = tg >> 11;
        const int tt = tg & 2047;
#pragma unroll
        for (int r = 0; r < 4; ++r) {
            int h = w * 16 + lhi * 4 + r;   // w repurposed as h group
            float v = sm.mv[0][h][l15] + sm.mv[1][h][l15] +
                      sm.mv[2][h][l15] + sm.mv[3][h][l15];
            vhT[(((size_t)(b * NH + h)) << 11) + tt] = (bf16_t)v;
        }
    }
}

// ---------------------------------------------------------------------------
// Kernel 2: split-K flash attention, causal + key-mask.
// grid = (B*T/16) linear blocks, 256 thr. Block owns ONE 16-row q-tile; its
// 4 waves split the causal key range 4 ways (64-key tiles each), then merge
// partial (m, l, O) through LDS.
// ---------------------------------------------------------------------------
__global__ __launch_bounds__(256) void attn_kernel(
    const bf16_t* __restrict__ qh, const bf16_t* __restrict__ kh,
    const bf16_t* __restrict__ vhT, const int* __restrict__ mask,
    float* __restrict__ out)
{
    const int lin  = blockIdx.x;
    const int qt16 = lin >> 3;     // 0..127: q-tile (16 rows)
    const int b    = lin & 7;
    const int w    = threadIdx.x >> 6;   // key-split index 0..3
    const int lane = threadIdx.x & 63;
    const int l15  = lane & 15;
    const int lhi  = lane >> 4;

    __shared__ __align__(16) char plds[4][2][2048];   // [wave][dbuf][16x64 bf16]
    __shared__ float sm_o[4][16][65];                  // [wave][row][col] (+1 pad)
    __shared__ float sm_ml[4][2][16];                  // [wave][m/l][row]

    const int q0  = qt16 * 16;
    const int nkt = (q0 + 15) / 64 + 1;     // causal 64-key tiles
    const int len = (nkt + 3) >> 2;         // ceil(nkt/4)
    const int kt_beg = w * len;
    const int kt_end = min(kt_beg + len, nkt);

    // Q fragments (H=64 -> two k-chunks of 32)
    const bf16_t* qbase = qh + (size_t)(b * NT + q0 + l15) * NH + lhi * 8;
    bf16x8 qf0 = *(const bf16x8*)(qbase);
    bf16x8 qf1 = *(const bf16x8*)(qbase + 32);

    f32x4 acc_o[4] = {fzero4(), fzero4(), fzero4(), fzero4()};
    float m[4]    = {-1e30f, -1e30f, -1e30f, -1e30f};
    float lsum[4] = {0.f, 0.f, 0.f, 0.f};

    const int qq0 = q0 + lhi * 4;  // this lane's first q-row

    for (int kt = kt_beg; kt < kt_end; ++kt) {
        // ---- S = (qh . kh^T) * 0.125, tile 16q x 64k --------------------
        const bf16_t* kbase = kh + (size_t)(b * NT + kt * 64 + l15) * NH + lhi * 8;
        f32x4 s[4] = {fzero4(), fzero4(), fzero4(), fzero4()};
#pragma unroll
        for (int cg = 0; cg < 4; ++cg) {
            bf16x8 kf0 = *(const bf16x8*)(kbase + (size_t)cg * 16 * NH);
            bf16x8 kf1 = *(const bf16x8*)(kbase + (size_t)cg * 16 * NH + 32);
            s[cg] = MFMA16(qf0, kf0, s[cg]);
            s[cg] = MFMA16(qf1, kf1, s[cg]);
        }

        // ---- mask + scale ----------------------------------------------
        int mk[4];
#pragma unroll
        for (int cg = 0; cg < 4; ++cg) mk[cg] = mask[b * NT + kt * 64 + cg * 16 + l15];
#pragma unroll
        for (int cg = 0; cg < 4; ++cg) {
            int kk = kt * 64 + cg * 16 + l15;
#pragma unroll
            for (int r = 0; r < 4; ++r) {
                float sv = s[cg][r] * 0.125f;
                bool ok = (kk <= qq0 + r) && (mk[cg] != 0);
                s[cg][r] = ok ? sv : -1e30f;
            }
        }

        // ---- online softmax (row spread over 16 lanes x 4 cgs) ----------
        float mx[4];
#pragma unroll
        for (int r = 0; r < 4; ++r) {
            mx[r] = fmaxf(fmaxf(s[0][r], s[1][r]), fmaxf(s[2][r], s[3][r]));
#pragma unroll
            for (int d = 1; d < 16; d <<= 1) mx[r] = fmaxf(mx[r], __shfl_xor(mx[r], d));
        }
        float resc[4];
#pragma unroll
        for (int r = 0; r < 4; ++r) {
            float mn = fmaxf(m[r], mx[r]);
            resc[r] = __expf(m[r] - mn);
            m[r] = mn;
        }
        float rs[4] = {0.f, 0.f, 0.f, 0.f};
#pragma unroll
        for (int cg = 0; cg < 4; ++cg)
#pragma unroll
            for (int r = 0; r < 4; ++r) {
                float sv = s[cg][r];
                float p = (sv > -5e29f) ? __expf(sv - m[r]) : 0.f;  // masked -> exactly 0
                s[cg][r] = p;
                rs[r] += p;
            }
#pragma unroll
        for (int r = 0; r < 4; ++r) {
#pragma unroll
            for (int d = 1; d < 16; d <<= 1) rs[r] += __shfl_xor(rs[r], d);
            lsum[r] = lsum[r] * resc[r] + rs[r];
        }
#pragma unroll
        for (int cg = 0; cg < 4; ++cg)
#pragma unroll
            for (int r = 0; r < 4; ++r) acc_o[cg][r] *= resc[r];

        // ---- P -> LDS (bf16, XOR swizzle: byte ^= (row&7)<<4) -----------
        char* pb = &plds[w][kt & 1][0];
#pragma unroll
        for (int cg = 0; cg < 4; ++cg)
#pragma unroll
            for (int r = 0; r < 4; ++r) {
                int row = lhi * 4 + r;
                int col = cg * 16 + l15;
                int byte = (row * 128 + col * 2) ^ ((row & 7) << 4);
                *(bf16_t*)(pb + byte) = (bf16_t)s[cg][r];
            }

        // ---- O += P . V  (A-frags from LDS, B-frags from vhT, contiguous)
        const bf16_t* vbase = vhT + ((size_t)(b * NH + l15) << 11) + kt * 64 + lhi * 8;
#pragma unroll
        for (int kc = 0; kc < 2; ++kc) {
            int row = l15;
            int byte = (row * 128 + kc * 64 + lhi * 16) ^ ((row & 7) << 4);
            bf16x8 pf = *(bf16x8*)(pb + byte);
#pragma unroll
            for (int cg = 0; cg < 4; ++cg) {
                bf16x8 vf = *(const bf16x8*)(vbase + ((size_t)cg * 16 << 11) + kc * 32);
                acc_o[cg] = MFMA16(pf, vf, acc_o[cg]);
            }
        }
    }

    // ---- write this wave's partials to LDS ------------------------------
#pragma unroll
    for (int cg = 0; cg < 4; ++cg)
#pragma unroll
        for (int r = 0; r < 4; ++r)
            sm_o[w][lhi * 4 + r][cg * 16 + l15] = acc_o[cg][r];
    if (l15 == 0) {
#pragma unroll
        for (int r = 0; r < 4; ++r) {
            sm_ml[w][0][lhi * 4 + r] = m[r];
            sm_ml[w][1][lhi * 4 + r] = lsum[r];
        }
    }
    __syncthreads();

    // ---- merge 4 splits; this thread covers col = w*16+l15, rows lhi*4+r
#pragma unroll
    for (int r = 0; r < 4; ++r) {
        int row = lhi * 4 + r;
        float mg = -1e30f;
#pragma unroll
        for (int s = 0; s < 4; ++s) mg = fmaxf(mg, sm_ml[s][0][row]);
        float lg = 0.f, og = 0.f;
#pragma unroll
        for (int s = 0; s < 4; ++s) {
            float e = __expf(sm_ml[s][0][row] - mg);
            lg += e * sm_ml[s][1][row];
            og += e * sm_o[s][row][w * 16 + l15];
        }
        out[(size_t)(b * NT + q0 + row) * NH + w * 16 + l15] = og / lg;
    }
}

// ---------------------------------------------------------------------------
extern "C" void kernel_launch(void* const* d_in, const int* in_sizes, int n_in,
                              void* d_out, int out_size, void* d_ws, size_t ws_size,
                              hipStream_t stream)
{
    const float* k_in = (const float*)d_in[0];
    const float* q_in = (const float*)d_in[1];
    const float* v_in = (const float*)d_in[2];
    const int*   mask = (const int*)d_in[3];
    const float* Wk   = (const float*)d_in[4];
    const float* Wq   = (const float*)d_in[5];
    const float* Wv   = (const float*)d_in[6];
    float* out = (float*)d_out;

    char* ws = (char*)d_ws;
    bf16_t* Wb  = (bf16_t*)ws;                       // 3*64*1024 bf16 = 384 KB
    bf16_t* qh  = (bf16_t*)(ws + 3 * NH * NE * 2);   // 16384*64 bf16 = 2 MB
    bf16_t* kh  = qh + (size_t)NB * NT * NH;
    bf16_t* vhT = kh + (size_t)NB * NT * NH;         // [8][64][2048] bf16 = 2 MB

    convw_kernel<<<dim3(32, 3), 256, 0, stream>>>(Wq, Wk, Wv, Wb);
    proj_kernel<<<dim3(NB * NT / 16, 3), 256, 0, stream>>>(q_in, k_in, v_in, Wb, qh, kh, vhT);
    attn_kernel<<<dim3(NB * NT / 16), 256, 0, stream>>>(qh, kh, vhT, mask, out);
}

// Round 11
// 85.158 us; speedup vs baseline: 1.3754x; 1.3754x over previous
//
#include <hip/hip_runtime.h>
#include <hip/hip_bf16.h>

#define NB 8
#define NT 2048
#define NE 1024
#define NH 64

typedef __bf16 bf16_t;
typedef __bf16 bf16x8 __attribute__((ext_vector_type(8)));
typedef float f32x4 __attribute__((ext_vector_type(4)));

#define MFMA16(a, b, c) __builtin_amdgcn_mfma_f32_16x16x32_bf16(a, b, c, 0, 0, 0)

static __device__ __forceinline__ f32x4 fzero4() {
    f32x4 z = {0.f, 0.f, 0.f, 0.f};
    return z;
}

// async global -> LDS, 16 B per lane. LDS dest is wave-uniform base + lane*16
// (HW rule, m104/m108); global src is per-lane (pre-swizzle goes on the src).
static __device__ __forceinline__ void gload_lds16(const void* gsrc, void* ldst) {
    __builtin_amdgcn_global_load_lds(
        (const __attribute__((address_space(1))) char*)gsrc,
        (__attribute__((address_space(3))) char*)ldst, 16, 0, 0);
}

// ---------------------------------------------------------------------------
// Kernel 0: convert W (f32) -> bf16 workspace. Wb layout: [0]=Wq, [1]=Wk, [2]=Wv
// ---------------------------------------------------------------------------
__global__ __launch_bounds__(256) void convw_kernel(
    const float* __restrict__ Wq, const float* __restrict__ Wk,
    const float* __restrict__ Wv, bf16_t* __restrict__ Wb)
{
    int src = blockIdx.y;
    const float* W = (src == 0) ? Wq : ((src == 1) ? Wk : Wv);
    int idx = (blockIdx.x * 256 + threadIdx.x) * 8;  // 32 blocks * 256 thr * 8 = 65536
    f32x4 a = *(const f32x4*)(W + idx);
    f32x4 b = *(const f32x4*)(W + idx + 4);
    bf16x8 o;
#pragma unroll
    for (int j = 0; j < 4; ++j) { o[j] = (bf16_t)a[j]; o[4 + j] = (bf16_t)b[j]; }
    *(bf16x8*)(Wb + (size_t)src * (NH * NE) + idx) = o;
}

// ---------------------------------------------------------------------------
// Kernel 1: projections, W-SHARED-VIA-LDS (R11).
// Empirical law from R2..R10: proj always runs at ~10.3 B/cy/CU, the per-CU
// vector-memory port ceiling (m13: 6.29 TB/s / 256 CU / 2.4 GHz). Duration
// == total request bytes / port rate. Prior rounds moved 585 MB because
// every wave privately re-fetched its W slice (393 MB of W for 192 MB of x).
// R11 stages W ONCE PER BLOCK through LDS: W traffic 393 -> 98 MB, total
// port bytes 585 -> 296 MB -> predicted ~46 us.
// Structure: grid (256, 3) = 768 blocks = exactly 3/CU. Block = 64 t-rows,
// 4 waves x 16 rows. K-loop: 32 steps of BK=32, double-buffered:
//   per step per wave: 2 gload_lds (own x rows, 2 KB) + 1 gload_lds (its
//   quarter of the shared W slice, 1 KB); one __syncthreads per step (m97
//   2-buffer structure; barrier's vmcnt drain = next buffer ready).
// LDS: x [2][4 waves][16r x 8ch x 16B] = 16 KB; W [2][4 kch][64 h][16B] = 8 KB.
// Swizzles (source-side, G21/m173): x chunk phys = logical ^ (row&7);
// W is chunk-major [kchunk][h] so the fragment read walks 16 consecutive
// h-slots (l15-spread across banks).
//   y=0: qh[t][h] = q . Wq   (A = x rows, B = W)
//   y=1: kh[t][h] = k . Wk
//   y=2: vhT[b][h][t] = v . Wv (A = W, B = x -> accumulator is [h][t])
// MFMA 16x16x32 conventions (m89/m91-verified):
//   A-frag: lane holds A[row=lane&15][k=(lane>>4)*8 + j]
//   B-frag: lane holds B[k=(lane>>4)*8 + j][col=lane&15]
//   D:      col = lane&15, row = (lane>>4)*4 + reg
// ---------------------------------------------------------------------------
__global__ __launch_bounds__(256) void proj_kernel(
    const float* __restrict__ q_in, const float* __restrict__ k_in,
    const float* __restrict__ v_in, const bf16_t* __restrict__ Wb,
    bf16_t* __restrict__ qh, bf16_t* __restrict__ kh, bf16_t* __restrict__ vhT)
{
    const int which = blockIdx.y;
    const int w    = threadIdx.x >> 6;   // wave 0..3: owns t-rows w*16..+16, stages W kchunk w
    const int lane = threadIdx.x & 63;
    const int l15  = lane & 15;
    const int lhi  = lane >> 4;
    const int t0   = blockIdx.x * 64;

    const float*  x = (which == 0) ? q_in : ((which == 1) ? k_in : v_in);
    const bf16_t* W = Wb + (size_t)which * (NH * NE);

    __shared__ __align__(16) char xlds[2][4][2048];  // [buf][wave][16 rows][8 ch][16B]
    __shared__ __align__(16) char wlds[2][4096];     // [buf][4 kchunk][64 h][16B]

    // ---- staging sources (per-lane, pre-swizzled; step adds k floats) ----
    // x instr i (i=0,1): rows i*8+(lane>>3) of this wave's 16; phys chunk lane&7
    const float* xsrc[2];
#pragma unroll
    for (int i = 0; i < 2; ++i) {
        int rw   = i * 8 + (lane >> 3);
        int phys = lane & 7;
        xsrc[i] = x + (size_t)(t0 + w * 16 + rw) * NE + ((phys ^ (rw & 7)) << 2);
    }
    // W instr: wave w stages kchunk w (k = w*8..w*8+7 of the 32-slice); lane = h
    const bf16_t* wsrc = W + (size_t)lane * NE + w * 8;

    // ---- fragment read byte-offsets (buffer-invariant) -------------------
    int xo[2];
#pragma unroll
    for (int j = 0; j < 2; ++j)
        xo[j] = l15 * 128 + ((((lhi * 2 + j) ^ (l15 & 7))) << 4);
    int wo[4];
#pragma unroll
    for (int cg = 0; cg < 4; ++cg)
        wo[cg] = lhi * 1024 + (cg * 16 + l15) * 16;

    f32x4 acc[4] = {fzero4(), fzero4(), fzero4(), fzero4()};

    // ---- prologue: stage step 0 into buf 0 -------------------------------
    gload_lds16(xsrc[0], &xlds[0][w][0]);
    gload_lds16(xsrc[1], &xlds[0][w][1024]);
    gload_lds16(wsrc, &wlds[0][w * 1024]);
    __syncthreads();

    // ---- K-loop: 32 steps of K=32, dbuf, one barrier/step ----------------
#pragma unroll 4
    for (int step = 0; step < 32; ++step) {
        const int cur = step & 1;
        if (step < 31) {
            const int k0 = (step + 1) * 32;
            gload_lds16(xsrc[0] + k0, &xlds[cur ^ 1][w][0]);
            gload_lds16(xsrc[1] + k0, &xlds[cur ^ 1][w][1024]);
            gload_lds16(wsrc + k0, &wlds[cur ^ 1][w * 1024]);
        }
        const char* xb = xlds[cur][w];
        const char* wb = wlds[cur];

        f32x4 a0 = *(const f32x4*)(xb + xo[0]);
        f32x4 a1 = *(const f32x4*)(xb + xo[1]);
        bf16x8 xf;
#pragma unroll
        for (int j = 0; j < 4; ++j) { xf[j] = (bf16_t)a0[j]; xf[4 + j] = (bf16_t)a1[j]; }

        if (which < 2) {
            acc[0] = MFMA16(xf, *(const bf16x8*)(wb + wo[0]), acc[0]);
            acc[1] = MFMA16(xf, *(const bf16x8*)(wb + wo[1]), acc[1]);
            acc[2] = MFMA16(xf, *(const bf16x8*)(wb + wo[2]), acc[2]);
            acc[3] = MFMA16(xf, *(const bf16x8*)(wb + wo[3]), acc[3]);
        } else {
            acc[0] = MFMA16(*(const bf16x8*)(wb + wo[0]), xf, acc[0]);
            acc[1] = MFMA16(*(const bf16x8*)(wb + wo[1]), xf, acc[1]);
            acc[2] = MFMA16(*(const bf16x8*)(wb + wo[2]), xf, acc[2]);
            acc[3] = MFMA16(*(const bf16x8*)(wb + wo[3]), xf, acc[3]);
        }
        __syncthreads();   // vmcnt drain at barrier: next buffer complete
    }

    // ---- epilogue ---------------------------------------------------------
    if (which < 2) {
        bf16_t* outp = (which == 0) ? qh : kh;
#pragma unroll
        for (int cg = 0; cg < 4; ++cg)
#pragma unroll
            for (int r = 0; r < 4; ++r) {
                int t = t0 + w * 16 + lhi * 4 + r;
                outp[(size_t)t * NH + cg * 16 + l15] = (bf16_t)acc[cg][r];
            }
    } else {
        // D (A=W): row = h within group (lhi*4+r), col = t within 16 (l15)
        const int tg = t0 + w * 16 + l15;
        const int b  = tg >> 11;
        const int tt = tg & 2047;
#pragma unroll
        for (int hg = 0; hg < 4; ++hg)
#pragma unroll
            for (int r = 0; r < 4; ++r) {
                int h = hg * 16 + lhi * 4 + r;
                vhT[(((size_t)(b * NH + h)) << 11) + tt] = (bf16_t)acc[hg][r];
            }
    }
}

// ---------------------------------------------------------------------------
// Kernel 2: split-K flash attention, causal + key-mask.
// grid = (B*T/16) linear blocks, 256 thr. Block owns ONE 16-row q-tile; its
// 4 waves split the causal key range 4 ways (64-key tiles each), then merge
// partial (m, l, O) through LDS.
// ---------------------------------------------------------------------------
__global__ __launch_bounds__(256) void attn_kernel(
    const bf16_t* __restrict__ qh, const bf16_t* __restrict__ kh,
    const bf16_t* __restrict__ vhT, const int* __restrict__ mask,
    float* __restrict__ out)
{
    const int lin  = blockIdx.x;
    const int qt16 = lin >> 3;     // 0..127: q-tile (16 rows)
    const int b    = lin & 7;
    const int w    = threadIdx.x >> 6;   // key-split index 0..3
    const int lane = threadIdx.x & 63;
    const int l15  = lane & 15;
    const int lhi  = lane >> 4;

    __shared__ __align__(16) char plds[4][2][2048];   // [wave][dbuf][16x64 bf16]
    __shared__ float sm_o[4][16][65];                  // [wave][row][col] (+1 pad)
    __shared__ float sm_ml[4][2][16];                  // [wave][m/l][row]

    const int q0  = qt16 * 16;
    const int nkt = (q0 + 15) / 64 + 1;     // causal 64-key tiles
    const int len = (nkt + 3) >> 2;         // ceil(nkt/4)
    const int kt_beg = w * len;
    const int kt_end = min(kt_beg + len, nkt);

    // Q fragments (H=64 -> two k-chunks of 32)
    const bf16_t* qbase = qh + (size_t)(b * NT + q0 + l15) * NH + lhi * 8;
    bf16x8 qf0 = *(const bf16x8*)(qbase);
    bf16x8 qf1 = *(const bf16x8*)(qbase + 32);

    f32x4 acc_o[4] = {fzero4(), fzero4(), fzero4(), fzero4()};
    float m[4]    = {-1e30f, -1e30f, -1e30f, -1e30f};
    float lsum[4] = {0.f, 0.f, 0.f, 0.f};

    const int qq0 = q0 + lhi * 4;  // this lane's first q-row

    for (int kt = kt_beg; kt < kt_end; ++kt) {
        // ---- S = (qh . kh^T) * 0.125, tile 16q x 64k --------------------
        const bf16_t* kbase = kh + (size_t)(b * NT + kt * 64 + l15) * NH + lhi * 8;
        f32x4 s[4] = {fzero4(), fzero4(), fzero4(), fzero4()};
#pragma unroll
        for (int cg = 0; cg < 4; ++cg) {
            bf16x8 kf0 = *(const bf16x8*)(kbase + (size_t)cg * 16 * NH);
            bf16x8 kf1 = *(const bf16x8*)(kbase + (size_t)cg * 16 * NH + 32);
            s[cg] = MFMA16(qf0, kf0, s[cg]);
            s[cg] = MFMA16(qf1, kf1, s[cg]);
        }

        // ---- mask + scale ----------------------------------------------
        int mk[4];
#pragma unroll
        for (int cg = 0; cg < 4; ++cg) mk[cg] = mask[b * NT + kt * 64 + cg * 16 + l15];
#pragma unroll
        for (int cg = 0; cg < 4; ++cg) {
            int kk = kt * 64 + cg * 16 + l15;
#pragma unroll
            for (int r = 0; r < 4; ++r) {
                float sv = s[cg][r] * 0.125f;
                bool ok = (kk <= qq0 + r) && (mk[cg] != 0);
                s[cg][r] = ok ? sv : -1e30f;
            }
        }

        // ---- online softmax (row spread over 16 lanes x 4 cgs) ----------
        float mx[4];
#pragma unroll
        for (int r = 0; r < 4; ++r) {
            mx[r] = fmaxf(fmaxf(s[0][r], s[1][r]), fmaxf(s[2][r], s[3][r]));
#pragma unroll
            for (int d = 1; d < 16; d <<= 1) mx[r] = fmaxf(mx[r], __shfl_xor(mx[r], d));
        }
        float resc[4];
#pragma unroll
        for (int r = 0; r < 4; ++r) {
            float mn = fmaxf(m[r], mx[r]);
            resc[r] = __expf(m[r] - mn);
            m[r] = mn;
        }
        float rs[4] = {0.f, 0.f, 0.f, 0.f};
#pragma unroll
        for (int cg = 0; cg < 4; ++cg)
#pragma unroll
            for (int r = 0; r < 4; ++r) {
                float sv = s[cg][r];
                float p = (sv > -5e29f) ? __expf(sv - m[r]) : 0.f;  // masked -> exactly 0
                s[cg][r] = p;
                rs[r] += p;
            }
#pragma unroll
        for (int r = 0; r < 4; ++r) {
#pragma unroll
            for (int d = 1; d < 16; d <<= 1) rs[r] += __shfl_xor(rs[r], d);
            lsum[r] = lsum[r] * resc[r] + rs[r];
        }
#pragma unroll
        for (int cg = 0; cg < 4; ++cg)
#pragma unroll
            for (int r = 0; r < 4; ++r) acc_o[cg][r] *= resc[r];

        // ---- P -> LDS (bf16, XOR swizzle: byte ^= (row&7)<<4) -----------
        char* pb = &plds[w][kt & 1][0];
#pragma unroll
        for (int cg = 0; cg < 4; ++cg)
#pragma unroll
            for (int r = 0; r < 4; ++r) {
                int row = lhi * 4 + r;
                int col = cg * 16 + l15;
                int byte = (row * 128 + col * 2) ^ ((row & 7) << 4);
                *(bf16_t*)(pb + byte) = (bf16_t)s[cg][r];
            }

        // ---- O += P . V  (A-frags from LDS, B-frags from vhT, contiguous)
        const bf16_t* vbase = vhT + ((size_t)(b * NH + l15) << 11) + kt * 64 + lhi * 8;
#pragma unroll
        for (int kc = 0; kc < 2; ++kc) {
            int row = l15;
            int byte = (row * 128 + kc * 64 + lhi * 16) ^ ((row & 7) << 4);
            bf16x8 pf = *(bf16x8*)(pb + byte);
#pragma unroll
            for (int cg = 0; cg < 4; ++cg) {
                bf16x8 vf = *(const bf16x8*)(vbase + ((size_t)cg * 16 << 11) + kc * 32);
                acc_o[cg] = MFMA16(pf, vf, acc_o[cg]);
            }
        }
    }

    // ---- write this wave's partials to LDS ------------------------------
#pragma unroll
    for (int cg = 0; cg < 4; ++cg)
#pragma unroll
        for (int r = 0; r < 4; ++r)
            sm_o[w][lhi * 4 + r][cg * 16 + l15] = acc_o[cg][r];
    if (l15 == 0) {
#pragma unroll
        for (int r = 0; r < 4; ++r) {
            sm_ml[w][0][lhi * 4 + r] = m[r];
            sm_ml[w][1][lhi * 4 + r] = lsum[r];
        }
    }
    __syncthreads();

    // ---- merge 4 splits; this thread covers col = w*16+l15, rows lhi*4+r
#pragma unroll
    for (int r = 0; r < 4; ++r) {
        int row = lhi * 4 + r;
        float mg = -1e30f;
#pragma unroll
        for (int s = 0; s < 4; ++s) mg = fmaxf(mg, sm_ml[s][0][row]);
        float lg = 0.f, og = 0.f;
#pragma unroll
        for (int s = 0; s < 4; ++s) {
            float e = __expf(sm_ml[s][0][row] - mg);
            lg += e * sm_ml[s][1][row];
            og += e * sm_o[s][row][w * 16 + l15];
        }
        out[(size_t)(b * NT + q0 + row) * NH + w * 16 + l15] = og / lg;
    }
}

// ---------------------------------------------------------------------------
extern "C" void kernel_launch(void* const* d_in, const int* in_sizes, int n_in,
                              void* d_out, int out_size, void* d_ws, size_t ws_size,
                              hipStream_t stream)
{
    const float* k_in = (const float*)d_in[0];
    const float* q_in = (const float*)d_in[1];
    const float* v_in = (const float*)d_in[2];
    const int*   mask = (const int*)d_in[3];
    const float* Wk   = (const float*)d_in[4];
    const float* Wq   = (const float*)d_in[5];
    const float* Wv   = (const float*)d_in[6];
    float* out = (float*)d_out;

    char* ws = (char*)d_ws;
    bf16_t* Wb  = (bf16_t*)ws;                       // 3*64*1024 bf16 = 384 KB
    bf16_t* qh  = (bf16_t*)(ws + 3 * NH * NE * 2);   // 16384*64 bf16 = 2 MB
    bf16_t* kh  = qh + (size_t)NB * NT * NH;
    bf16_t* vhT = kh + (size_t)NB * NT * NH;         // [8][64][2048] bf16 = 2 MB

    convw_kernel<<<dim3(32, 3), 256, 0, stream>>>(Wq, Wk, Wv, Wb);
    proj_kernel<<<dim3(NB * NT / 64, 3), 256, 0, stream>>>(q_in, k_in, v_in, Wb, qh, kh, vhT);
    attn_kernel<<<dim3(NB * NT / 16), 256, 0, stream>>>(qh, kh, vhT, mask, out);
}